// Round 19
// baseline (54.157 us; speedup 1.0000x reference)
//
#include <hip/hip_runtime.h>
#include <hip/hip_bf16.h>

#define NROWS 4096
#define DIM   1024
#define ROWB8 1024           // bytes per row, int8
#define ROWB4 512            // bytes per row, fp4
#define BT    256            // full tile edge
#define BH    128            // half-tile column width
#define BK8   128            // int8 K-step bytes (= 128 k)
#define NKT8  (DIM / 128)    // 8 int8 K-steps
#define BKB4  128            // fp4 K-step bytes per row (= 256 k)
#define NKT4  (DIM / 256)    // 4 fp4 K-steps
#define NTB   (NROWS / BT)   // 16
#define NOFF  240            // 120 strict-upper tiles x 2 column-halves
#define TEMP_INV 10.0f
#define INV_S8 3.814697e-6f  // 1/(512*512)
#define INV_S4 9.765625e-4f  // 1/(32*32)
#define SCALE1 0x7F7F7F7F    // E8M0 1.0 (validated R11/R13)

typedef int i32x4 __attribute__((ext_vector_type(4)));
typedef int i32x8 __attribute__((ext_vector_type(8)));

__device__ __forceinline__ void gload16(const void* g, void* l) {
    __builtin_amdgcn_global_load_lds(
        (const __attribute__((address_space(1))) void*)g,
        (__attribute__((address_space(3))) void*)l, 16, 0, 0);
}

// e2m1 quantize, round-to-nearest (proven R13, absmax 0.0).
__device__ __forceinline__ unsigned qfp4(float x) {
    const float m = fabsf(x);
    const unsigned c = (unsigned)(m >= 0.25f) + (unsigned)(m >= 0.75f)
                     + (unsigned)(m >= 1.25f) + (unsigned)(m >= 1.75f)
                     + (unsigned)(m >= 2.5f)  + (unsigned)(m >= 3.5f)
                     + (unsigned)(m >= 5.0f);
    return c | (x < 0.0f ? 8u : 0u);
}

// Row-normalize fp32 -> int8 (x512, proven R15) AND fp4 e2m1 (x32, proven
// R13); zeroes this row's partial accumulators.
__global__ __launch_bounds__(256) void normalize_k(const float* __restrict__ pred,
                                                   unsigned char* __restrict__ xn8,
                                                   unsigned short* __restrict__ xn4,
                                                   float* __restrict__ posw,
                                                   float* __restrict__ denw) {
    const int row = blockIdx.x;
    const int tid = threadIdx.x;
    const float4 v = reinterpret_cast<const float4*>(pred + (size_t)row * DIM)[tid];
    float ss = v.x * v.x + v.y * v.y + v.z * v.z + v.w * v.w;
    #pragma unroll
    for (int off = 32; off; off >>= 1) ss += __shfl_xor(ss, off, 64);
    __shared__ float red[4];
    if ((tid & 63) == 0) red[tid >> 6] = ss;
    __syncthreads();
    const float tot = red[0] + red[1] + red[2] + red[3];
    const float inv = 1.0f / fmaxf(sqrtf(tot), 1e-8f);
    // int8 (x512)
    const float s8 = 512.0f * inv;
    int q0 = __float2int_rn(v.x * s8), q1 = __float2int_rn(v.y * s8);
    int q2 = __float2int_rn(v.z * s8), q3 = __float2int_rn(v.w * s8);
    q0 = min(max(q0, -127), 127); q1 = min(max(q1, -127), 127);
    q2 = min(max(q2, -127), 127); q3 = min(max(q3, -127), 127);
    reinterpret_cast<int*>(xn8)[row * (DIM / 4) + tid] =
        (q0 & 0xFF) | ((q1 & 0xFF) << 8) | ((q2 & 0xFF) << 16) | ((q3 & 0xFF) << 24);
    // fp4 (x32)
    const float s4 = 32.0f * inv;
    const unsigned f0 = qfp4(v.x * s4), f1 = qfp4(v.y * s4);
    const unsigned f2 = qfp4(v.z * s4), f3 = qfp4(v.w * s4);
    xn4[row * (ROWB4 / 2) + tid] =
        (unsigned short)(f0 | (f1 << 4) | (f2 << 8) | (f3 << 12));
    if (tid == 0) { posw[row] = 0.0f; denw[row] = 0.0f; }
}

#define BAR asm volatile("s_barrier" ::: "memory")

// Mixed-precision triangular Gram + contrastive epilogue, 256 blocks:
//   ids 0..239  : off-diag column-half (256x128) in FP4 (mfma_scale
//                 16x16x128, scale=1.0; layout proven R13).  48KB/step x
//                 4 steps (K=256/step).  acc[4][4] = 64 VGPR -> fits the
//                 (512,2) 128-cap (mfma_scale can't use AGPRs — R13/R14's
//                 spill was acc[8][4]=128).  Col-side + mirror row-side.
//   ids 240..255: diag tile (256^2) in INT8 — R17's proven path unchanged
//                 (acc in AGPRs, no spill).  32KB/step x 8 steps, B == A.
// Staged bytes 96 -> 50 MB against the measured ~24.6 GB/s/CU ingest
// ceiling (R15/R17/R18: depth-independent).
__global__ __launch_bounds__(512, 2) void fused_gram(
        const unsigned char* __restrict__ xn8,
        const unsigned char* __restrict__ xn4,
        const int* __restrict__ tgt,
        float* __restrict__ posw, float* __restrict__ denw) {
    __shared__ unsigned char As[2][BT * 128];   // 2 x 32 KB
    __shared__ unsigned char Bs[2][BH * 128];   // 2 x 16 KB  (96 KB)

    const int tid = threadIdx.x;
    const int w   = tid >> 6;
    const int l   = tid & 63;
    const int l15 = l & 15;
    const int kgl = l >> 4;
    const int swz = l15 & 7;

    int xr[2];
    #pragma unroll
    for (int s = 0; s < 2; ++s) xr[s] = ((s * 4 + kgl) ^ swz) * 16;

    if ((int)blockIdx.x < NOFF) {
        // ------------- off-diagonal column-half, FP4 -------------
        const int t = ((int)blockIdx.x & 7) * (NOFF / 8) + ((int)blockIdx.x >> 3);
        const int tau = t >> 1, half = t & 1;
        int bi = 0, rem = tau;
        while (rem >= NTB - 1 - bi) { rem -= NTB - 1 - bi; ++bi; }
        const int bj = bi + 1 + rem;
        const int rowbase = bi * BT;
        const int colbase = bj * BT + half * BH;

        const int wm = w >> 1;       // 0..3 (64-row band)
        const int wn = w & 1;        // 0..1 (64-col band)

        const unsigned char* arow = xn4 + (size_t)rowbase * ROWB4;
        const unsigned char* bcol = xn4 + (size_t)colbase * ROWB4;

        int rowA[4], rowB[4];
        #pragma unroll
        for (int fi = 0; fi < 4; ++fi) rowA[fi] = (wm * 64 + fi * 16 + l15) * 128;
        #pragma unroll
        for (int fj = 0; fj < 4; ++fj) rowB[fj] = (wn * 64 + fj * 16 + l15) * 128;

        float acc[4][4][4];   // logical f32x4 per cell, 64 VGPR
        typedef float f32x4 __attribute__((ext_vector_type(4)));
        f32x4* accv = reinterpret_cast<f32x4*>(acc);
        #pragma unroll
        for (int i = 0; i < 16; ++i) accv[i] = (f32x4){0.f, 0.f, 0.f, 0.f};

        // A: 256 rows x 128 B = 2048 granules -> 4 loads/thr; B: 128 rows -> 2.
#define STAGE_OD(kt_, s_)                                                      \
    do {                                                                       \
        _Pragma("unroll")                                                      \
        for (int c = 0; c < 4; ++c) {                                          \
            const int p = c * 512 + tid, r = p >> 3, kg = (p & 7) ^ (r & 7);   \
            gload16(arow + (size_t)r * ROWB4 + (kt_) * BKB4 + kg * 16,         \
                    &As[s_][p * 16]);                                          \
        }                                                                      \
        _Pragma("unroll")                                                      \
        for (int c = 0; c < 2; ++c) {                                          \
            const int p = c * 512 + tid, r = p >> 3, kg = (p & 7) ^ (r & 7);   \
            gload16(bcol + (size_t)r * ROWB4 + (kt_) * BKB4 + kg * 16,         \
                    &Bs[s_][p * 16]);                                          \
        }                                                                      \
    } while (0)

        STAGE_OD(0, 0);
        for (int kt = 0; kt < NKT4; ++kt) {
            const int cur = kt & 1;
            if (kt + 1 < NKT4) {
                STAGE_OD(kt + 1, cur ^ 1);
                asm volatile("s_waitcnt vmcnt(6)" ::: "memory");
            } else {
                asm volatile("s_waitcnt vmcnt(0)" ::: "memory");
            }
            BAR;
            const unsigned char* as = &As[cur][0];
            const unsigned char* bs = &Bs[cur][0];
            #pragma unroll
            for (int m = 0; m < 2; ++m) {        // two K=128 slices per step
                #pragma unroll
                for (int fjh = 0; fjh < 4; fjh += 2) {   // b pairs: low pressure
                    i32x8 b2[2];
                    #pragma unroll
                    for (int v2 = 0; v2 < 2; ++v2) {
                        const i32x4 p = *reinterpret_cast<const i32x4*>(
                            &bs[rowB[fjh + v2] + xr[m]]);
                        i32x8 r; r[0]=p[0]; r[1]=p[1]; r[2]=p[2]; r[3]=p[3];
                                 r[4]=p[0]; r[5]=p[1]; r[6]=p[2]; r[7]=p[3];
                        b2[v2] = r;
                    }
                    #pragma unroll
                    for (int fih = 0; fih < 4; fih += 2) {
                        i32x8 a2[2];
                        #pragma unroll
                        for (int u = 0; u < 2; ++u) {
                            const i32x4 p = *reinterpret_cast<const i32x4*>(
                                &as[rowA[fih + u] + xr[m]]);
                            i32x8 r; r[0]=p[0]; r[1]=p[1]; r[2]=p[2]; r[3]=p[3];
                                     r[4]=p[0]; r[5]=p[1]; r[6]=p[2]; r[7]=p[3];
                            a2[u] = r;
                        }
                        __builtin_amdgcn_s_setprio(1);
                        #pragma unroll
                        for (int u = 0; u < 2; ++u)
                            #pragma unroll
                            for (int v2 = 0; v2 < 2; ++v2) {
                                f32x4* c = reinterpret_cast<f32x4*>(
                                    acc[fih + u][fjh + v2]);
                                *c = __builtin_amdgcn_mfma_scale_f32_16x16x128_f8f6f4(
                                    a2[u], b2[v2], *c,
                                    4, 4, 0, SCALE1, 0, SCALE1);
                            }
                        __builtin_amdgcn_s_setprio(0);
                    }
                }
            }
            BAR;
        }
#undef STAGE_OD

        // Epilogue: col-side + mirror row-side (verified R2/R16/R17).
        int jc[4], tj[4];
        #pragma unroll
        for (int fj = 0; fj < 4; ++fj) {
            jc[fj] = colbase + wn * 64 + fj * 16 + l15;
            tj[fj] = tgt[jc[fj]];
        }
        float denc[4] = {0.f, 0.f, 0.f, 0.f};
        float posc[4] = {0.f, 0.f, 0.f, 0.f};
        #pragma unroll
        for (int fi = 0; fi < 4; ++fi) {
            const int ribase = rowbase + wm * 64 + fi * 16 + (l >> 4) * 4;
            const int4 tiv = *reinterpret_cast<const int4*>(&tgt[ribase]);
            const int tia[4] = {tiv.x, tiv.y, tiv.z, tiv.w};
            float denr[4] = {0.f, 0.f, 0.f, 0.f};
            float posr[4] = {0.f, 0.f, 0.f, 0.f};
            #pragma unroll
            for (int q = 0; q < 4; ++q) {
                const int ti = tia[q];
                #pragma unroll
                for (int fj = 0; fj < 4; ++fj) {
                    const float sv = acc[fi][fj][q] * INV_S4;
                    const float pc = fmaxf(sv, 1e-10f);
                    const float e  = __expf(TEMP_INV * pc);
                    if (ti != tj[fj]) { denc[fj] += e;  denr[q] += e; }
                    else              { posc[fj] += pc; posr[q] += pc; }
                }
            }
            #pragma unroll
            for (int q = 0; q < 4; ++q) {
                #pragma unroll
                for (int off = 1; off < 16; off <<= 1) {
                    denr[q] += __shfl_xor(denr[q], off, 64);
                    posr[q] += __shfl_xor(posr[q], off, 64);
                }
            }
            if (l15 == 0) {
                #pragma unroll
                for (int q = 0; q < 4; ++q) {
                    atomicAdd(&denw[ribase + q], denr[q]);
                    atomicAdd(&posw[ribase + q], posr[q]);
                }
            }
        }
        #pragma unroll
        for (int fj = 0; fj < 4; ++fj) {
            #pragma unroll
            for (int off = 16; off < 64; off <<= 1) {
                denc[fj] += __shfl_xor(denc[fj], off, 64);
                posc[fj] += __shfl_xor(posc[fj], off, 64);
            }
            if (l < 16) {
                atomicAdd(&denw[jc[fj]], denc[fj]);
                atomicAdd(&posw[jc[fj]], posc[fj]);
            }
        }
    } else {
        // ------------- diagonal tile, INT8 (R17 proven, unchanged) -------------
        const int d = (int)blockIdx.x - NOFF;
        const int rowbase = d * BT;
        const int colbase = rowbase;
        const int wr = w >> 2;
        const int wc = w & 3;

        const unsigned char* arow = xn8 + (size_t)rowbase * ROWB8;

        int rowA[8], rowB[4];
        #pragma unroll
        for (int fi = 0; fi < 8; ++fi) rowA[fi] = (wr * 128 + fi * 16 + l15) * BK8;
        #pragma unroll
        for (int fj = 0; fj < 4; ++fj) rowB[fj] = (wc * 64 + fj * 16 + l15) * BK8;

        i32x4 acc[8][4];
        #pragma unroll
        for (int i = 0; i < 8; ++i)
            #pragma unroll
            for (int j = 0; j < 4; ++j) acc[i][j] = (i32x4){0, 0, 0, 0};

#define STAGE_DG(kt_, s_)                                                      \
    do {                                                                       \
        _Pragma("unroll")                                                      \
        for (int c = 0; c < 4; ++c) {                                          \
            const int p = c * 512 + tid, r = p >> 3, kg = (p & 7) ^ (r & 7);   \
            gload16(arow + (size_t)r * ROWB8 + (kt_) * BK8 + kg * 16,          \
                    &As[s_][p * 16]);                                          \
        }                                                                      \
    } while (0)

        STAGE_DG(0, 0);
        for (int kt = 0; kt < NKT8; ++kt) {
            const int cur = kt & 1;
            if (kt + 1 < NKT8) {
                STAGE_DG(kt + 1, cur ^ 1);
                asm volatile("s_waitcnt vmcnt(4)" ::: "memory");
            } else {
                asm volatile("s_waitcnt vmcnt(0)" ::: "memory");
            }
            BAR;
            const unsigned char* as = &As[cur][0];
            #pragma unroll
            for (int s = 0; s < 2; ++s) {
                i32x4 a[8], b[4];
                #pragma unroll
                for (int fi = 0; fi < 8; ++fi)
                    a[fi] = *reinterpret_cast<const i32x4*>(&as[rowA[fi] + xr[s]]);
                #pragma unroll
                for (int fj = 0; fj < 4; ++fj)
                    b[fj] = *reinterpret_cast<const i32x4*>(&as[rowB[fj] + xr[s]]);
                __builtin_amdgcn_s_setprio(1);
                #pragma unroll
                for (int fi = 0; fi < 8; ++fi)
                    #pragma unroll
                    for (int fj = 0; fj < 4; ++fj)
                        acc[fi][fj] = __builtin_amdgcn_mfma_i32_16x16x64_i8(
                            a[fi], b[fj], acc[fi][fj], 0, 0, 0);
                __builtin_amdgcn_s_setprio(0);
            }
            BAR;
        }
#undef STAGE_DG

        int jc[4], tj[4];
        #pragma unroll
        for (int fj = 0; fj < 4; ++fj) {
            jc[fj] = colbase + wc * 64 + fj * 16 + l15;
            tj[fj] = tgt[jc[fj]];
        }
        float denc[4] = {0.f, 0.f, 0.f, 0.f};
        float posc[4] = {0.f, 0.f, 0.f, 0.f};
        #pragma unroll
        for (int fi = 0; fi < 8; ++fi) {
            const int ribase = rowbase + wr * 128 + fi * 16 + (l >> 4) * 4;
            const int4 tiv = *reinterpret_cast<const int4*>(&tgt[ribase]);
            const int tia[4] = {tiv.x, tiv.y, tiv.z, tiv.w};
            #pragma unroll
            for (int q = 0; q < 4; ++q) {
                const int gi = ribase + q;
                const int ti = tia[q];
                #pragma unroll
                for (int fj = 0; fj < 4; ++fj) {
                    const float sv = (float)acc[fi][fj][q] * INV_S8;
                    const float pc = fmaxf(sv, 1e-10f);
                    const float e  = __expf(TEMP_INV * pc);
                    if (ti != tj[fj])        denc[fj] += e;
                    else if (gi != jc[fj])   posc[fj] += pc;
                }
            }
        }
        #pragma unroll
        for (int fj = 0; fj < 4; ++fj) {
            #pragma unroll
            for (int off = 16; off < 64; off <<= 1) {
                denc[fj] += __shfl_xor(denc[fj], off, 64);
                posc[fj] += __shfl_xor(posc[fj], off, 64);
            }
            if (l < 16) {
                atomicAdd(&denw[jc[fj]], denc[fj]);
                atomicAdd(&posw[jc[fj]], posc[fj]);
            }
        }
    }
}

// Single-block finalize (proven).
__global__ __launch_bounds__(1024) void finalize_k(const float* __restrict__ posw,
                                                   const float* __restrict__ denw,
                                                   const int* __restrict__ tgt,
                                                   float* __restrict__ out) {
    __shared__ int hist[128];
    __shared__ float red[16];
    const int tid = threadIdx.x;
    if (tid < 128) hist[tid] = 0;
    __syncthreads();
    const int4 t4 = reinterpret_cast<const int4*>(tgt)[tid];
    atomicAdd(&hist[t4.x], 1);
    atomicAdd(&hist[t4.y], 1);
    atomicAdd(&hist[t4.z], 1);
    atomicAdd(&hist[t4.w], 1);
    __syncthreads();
    const int ta[4] = {t4.x, t4.y, t4.z, t4.w};
    float v = 0.0f;
    #pragma unroll
    for (int q = 0; q < 4; ++q) {
        const int j = tid * 4 + q;
        const float d = fmaxf(denw[j], 1e-10f);
        const float c = (float)(hist[ta[q]] - 1);
        v += TEMP_INV * posw[j] - c * __logf(d);
    }
    #pragma unroll
    for (int off = 32; off; off >>= 1) v += __shfl_xor(v, off, 64);
    if ((tid & 63) == 0) red[tid >> 6] = v;
    __syncthreads();
    if (tid == 0) {
        float s = 0.0f;
        #pragma unroll
        for (int i = 0; i < 16; ++i) s += red[i];
        out[0] = -s * (1.0f / 4096.0f);
    }
}

extern "C" void kernel_launch(void* const* d_in, const int* in_sizes, int n_in,
                              void* d_out, int out_size, void* d_ws, size_t ws_size,
                              hipStream_t stream) {
    const float* pred = (const float*)d_in[0];
    const int*   tgt  = (const int*)d_in[1];
    float* out = (float*)d_out;

    unsigned char*  xn8 = (unsigned char*)d_ws;                       // 4 MB
    unsigned short* xn4 = (unsigned short*)((char*)d_ws + (size_t)NROWS * ROWB8);  // 2 MB
    float* posw = (float*)((char*)d_ws + (size_t)NROWS * (ROWB8 + ROWB4));
    float* denw = posw + NROWS;

    normalize_k<<<NROWS, 256, 0, stream>>>(pred, xn8, xn4, posw, denw);

    fused_gram<<<256, 512, 0, stream>>>(xn8, (const unsigned char*)xn4,
                                        tgt, posw, denw);

    finalize_k<<<1, 1024, 0, stream>>>(posw, denw, tgt, out);
}

// Round 20
// 44.718 us; speedup vs baseline: 1.2111x; 1.2111x over previous
//
#include <hip/hip_runtime.h>
#include <hip/hip_bf16.h>

#define NROWS 4096
#define DIM   1024           // K elements; 1024 B/row in int8
#define BT    256            // full tile edge
#define BH    128            // half-tile column width
#define BK    128            // K-step (128 B = 128 k-elems)
#define NKT   (DIM / BK)     // 8 K-steps
#define NTB   (NROWS / BT)   // 16
#define NOFF  240            // 120 strict-upper tiles x 2 column-halves
#define TEMP_INV 10.0f
#define INV_S 3.814697e-6f   // 1/(512*512): int8 stored as round(512*x)

typedef int i32x4 __attribute__((ext_vector_type(4)));

__device__ __forceinline__ void gload16(const void* g, void* l) {
    __builtin_amdgcn_global_load_lds(
        (const __attribute__((address_space(1))) void*)g,
        (__attribute__((address_space(3))) void*)l, 16, 0, 0);
}

// Row-normalize fp32 -> int8 (round(512*x/||x||), clamp +-127); zeroes
// this row's partial accumulators.  (Proven: R15/R17 absmax 0.0.)
__global__ __launch_bounds__(256) void normalize_k(const float* __restrict__ pred,
                                                   unsigned char* __restrict__ xn,
                                                   float* __restrict__ posw,
                                                   float* __restrict__ denw) {
    const int row = blockIdx.x;
    const int tid = threadIdx.x;
    const float4 v = reinterpret_cast<const float4*>(pred + (size_t)row * DIM)[tid];
    float ss = v.x * v.x + v.y * v.y + v.z * v.z + v.w * v.w;
    #pragma unroll
    for (int off = 32; off; off >>= 1) ss += __shfl_xor(ss, off, 64);
    __shared__ float red[4];
    if ((tid & 63) == 0) red[tid >> 6] = ss;
    __syncthreads();
    const float tot = red[0] + red[1] + red[2] + red[3];
    const float scale = 512.0f / fmaxf(sqrtf(tot), 1e-8f);
    int q0 = __float2int_rn(v.x * scale);
    int q1 = __float2int_rn(v.y * scale);
    int q2 = __float2int_rn(v.z * scale);
    int q3 = __float2int_rn(v.w * scale);
    q0 = min(max(q0, -127), 127); q1 = min(max(q1, -127), 127);
    q2 = min(max(q2, -127), 127); q3 = min(max(q3, -127), 127);
    const int pk = (q0 & 0xFF) | ((q1 & 0xFF) << 8) |
                   ((q2 & 0xFF) << 16) | ((q3 & 0xFF) << 24);
    reinterpret_cast<int*>(xn)[row * (DIM / 4) + tid] = pk;
    if (tid == 0) { posw[row] = 0.0f; denw[row] = 0.0f; }
}

#define BAR asm volatile("s_barrier" ::: "memory")

// Triangular int8 Gram + contrastive epilogue, 256 blocks x 1024 threads
// (16 waves/block).  KEY CHANGE vs R17: staging throughput scales with
// ISSUING WAVES (~3.1 GB/s/wave: R2/R15/R17 8-wave = 25 GB/s/CU; m97
// 16-wave = 52 GB/s/CU).  Doubling waves/CU halves staging time; the
// tile geometry, swizzle, vmcnt ledger, and epilogues are R17's proven
// pieces re-indexed for 4x4 wave grids.
//   ids 0..239  : off-diag column-half (256x128), wave tile 64x32,
//                 acc[4][2]=32 regs; stages A 32KB + B 16KB per step
//                 (3 loads/thread), vmcnt(3); col-side + mirror row-side.
//   ids 240..255: diag tile (256^2, B==A), wave tile 64x64, acc[4][4]=64;
//                 stages A 32KB (2 loads/thread), vmcnt(2); col-side only.
// __launch_bounds__(1024,1): 16 waves / 4 SIMD = 4 waves/SIMD -> 128-VGPR
// budget (explicit; R16 showed the no-bounds default caps at 64 -> spill).
__global__ __launch_bounds__(1024, 1) void fused_gram(
        const unsigned char* __restrict__ xn, const int* __restrict__ tgt,
        float* __restrict__ posw, float* __restrict__ denw) {
    __shared__ unsigned char As[2][BT * BK];   // 2 x 32 KB
    __shared__ unsigned char Bs[2][BH * BK];   // 2 x 16 KB  (96 KB total)

    const int tid = threadIdx.x;
    const int w   = tid >> 6;    // 0..15
    const int l   = tid & 63;
    const int l15 = l & 15;
    const int kgl = l >> 4;
    const int swz = l15 & 7;

    int xr[2];
    #pragma unroll
    for (int s = 0; s < 2; ++s) xr[s] = ((s * 4 + kgl) ^ swz) * 16;

    if ((int)blockIdx.x < NOFF) {
        // ---------------- off-diagonal column-half ----------------
        const int t = ((int)blockIdx.x & 7) * (NOFF / 8) + ((int)blockIdx.x >> 3);
        const int tau = t >> 1, half = t & 1;
        int bi = 0, rem = tau;
        while (rem >= NTB - 1 - bi) { rem -= NTB - 1 - bi; ++bi; }
        const int bj = bi + 1 + rem;
        const int rowbase = bi * BT;
        const int colbase = bj * BT + half * BH;

        const int wm = w >> 2;       // 0..3 (64-row band)
        const int wn = w & 3;        // 0..3 (32-col band)

        const unsigned char* arow = xn + (size_t)rowbase * DIM;
        const unsigned char* bcol = xn + (size_t)colbase * DIM;

        int rowA[4], rowB[2];
        #pragma unroll
        for (int fi = 0; fi < 4; ++fi) rowA[fi] = (wm * 64 + fi * 16 + l15) * BK;
        #pragma unroll
        for (int fj = 0; fj < 2; ++fj) rowB[fj] = (wn * 32 + fj * 16 + l15) * BK;

        i32x4 acc[4][2];
        #pragma unroll
        for (int i = 0; i < 4; ++i)
            #pragma unroll
            for (int j = 0; j < 2; ++j) acc[i][j] = (i32x4){0, 0, 0, 0};

#define STAGE_OD(kt_, s_)                                                      \
    do {                                                                       \
        _Pragma("unroll")                                                      \
        for (int c = 0; c < 2; ++c) {                                          \
            const int p = c * 1024 + tid, r = p >> 3, kg = (p & 7) ^ (r & 7);  \
            gload16(arow + (size_t)r * DIM + (kt_) * BK + kg * 16,             \
                    &As[s_][p * 16]);                                          \
        }                                                                      \
        {                                                                      \
            const int p = tid, r = p >> 3, kg = (p & 7) ^ (r & 7);             \
            gload16(bcol + (size_t)r * DIM + (kt_) * BK + kg * 16,             \
                    &Bs[s_][p * 16]);                                          \
        }                                                                      \
    } while (0)

        STAGE_OD(0, 0);
        for (int kt = 0; kt < NKT; ++kt) {
            const int cur = kt & 1;
            if (kt + 1 < NKT) {
                STAGE_OD(kt + 1, cur ^ 1);
                asm volatile("s_waitcnt vmcnt(3)" ::: "memory");   // kt landed
            } else {
                asm volatile("s_waitcnt vmcnt(0)" ::: "memory");
            }
            BAR;
            const unsigned char* as = &As[cur][0];
            const unsigned char* bs = &Bs[cur][0];
            #pragma unroll
            for (int s = 0; s < 2; ++s) {
                i32x4 a[4], b[2];
                #pragma unroll
                for (int fi = 0; fi < 4; ++fi)
                    a[fi] = *reinterpret_cast<const i32x4*>(&as[rowA[fi] + xr[s]]);
                #pragma unroll
                for (int fj = 0; fj < 2; ++fj)
                    b[fj] = *reinterpret_cast<const i32x4*>(&bs[rowB[fj] + xr[s]]);
                __builtin_amdgcn_s_setprio(1);
                #pragma unroll
                for (int fi = 0; fi < 4; ++fi)
                    #pragma unroll
                    for (int fj = 0; fj < 2; ++fj)
                        acc[fi][fj] = __builtin_amdgcn_mfma_i32_16x16x64_i8(
                            a[fi], b[fj], acc[fi][fj], 0, 0, 0);
                __builtin_amdgcn_s_setprio(0);
            }
            BAR;
        }
#undef STAGE_OD

        // Epilogue: col-side + mirror row-side (verified geometry, re-indexed).
        int jc[2], tj[2];
        #pragma unroll
        for (int fj = 0; fj < 2; ++fj) {
            jc[fj] = colbase + wn * 32 + fj * 16 + l15;
            tj[fj] = tgt[jc[fj]];
        }
        float denc[2] = {0.f, 0.f};
        float posc[2] = {0.f, 0.f};
        #pragma unroll
        for (int fi = 0; fi < 4; ++fi) {
            const int ribase = rowbase + wm * 64 + fi * 16 + (l >> 4) * 4;
            const int4 tiv = *reinterpret_cast<const int4*>(&tgt[ribase]);
            const int tia[4] = {tiv.x, tiv.y, tiv.z, tiv.w};
            float denr[4] = {0.f, 0.f, 0.f, 0.f};
            float posr[4] = {0.f, 0.f, 0.f, 0.f};
            #pragma unroll
            for (int q = 0; q < 4; ++q) {
                const int ti = tia[q];
                #pragma unroll
                for (int fj = 0; fj < 2; ++fj) {
                    const float sv = (float)acc[fi][fj][q] * INV_S;
                    const float pc = fmaxf(sv, 1e-10f);
                    const float e  = __expf(TEMP_INV * pc);
                    if (ti != tj[fj]) { denc[fj] += e;  denr[q] += e; }
                    else              { posc[fj] += pc; posr[q] += pc; }
                }
            }
            // Mirror: lanes sharing a row differ in bits 0-3.
            #pragma unroll
            for (int q = 0; q < 4; ++q) {
                #pragma unroll
                for (int off = 1; off < 16; off <<= 1) {
                    denr[q] += __shfl_xor(denr[q], off, 64);
                    posr[q] += __shfl_xor(posr[q], off, 64);
                }
            }
            if (l15 == 0) {
                #pragma unroll
                for (int q = 0; q < 4; ++q) {
                    atomicAdd(&denw[ribase + q], denr[q]);
                    atomicAdd(&posw[ribase + q], posr[q]);
                }
            }
        }
        // Col-side: lanes sharing a column differ in bits 4-5.
        #pragma unroll
        for (int fj = 0; fj < 2; ++fj) {
            #pragma unroll
            for (int off = 16; off < 64; off <<= 1) {
                denc[fj] += __shfl_xor(denc[fj], off, 64);
                posc[fj] += __shfl_xor(posc[fj], off, 64);
            }
            if (l < 16) {
                atomicAdd(&denw[jc[fj]], denc[fj]);
                atomicAdd(&posw[jc[fj]], posc[fj]);
            }
        }
    } else {
        // ---------------- diagonal tile (full 256^2, B == A) ----------------
        const int d = (int)blockIdx.x - NOFF;
        const int rowbase = d * BT;
        const int colbase = rowbase;
        const int wr = w >> 2;       // 0..3 (64-row band)
        const int wc = w & 3;        // 0..3 (64-col band)

        const unsigned char* arow = xn + (size_t)rowbase * DIM;

        int rowA[4], rowB[4];
        #pragma unroll
        for (int fi = 0; fi < 4; ++fi) rowA[fi] = (wr * 64 + fi * 16 + l15) * BK;
        #pragma unroll
        for (int fj = 0; fj < 4; ++fj) rowB[fj] = (wc * 64 + fj * 16 + l15) * BK;

        i32x4 acc[4][4];
        #pragma unroll
        for (int i = 0; i < 4; ++i)
            #pragma unroll
            for (int j = 0; j < 4; ++j) acc[i][j] = (i32x4){0, 0, 0, 0};

#define STAGE_DG(kt_, s_)                                                      \
    do {                                                                       \
        _Pragma("unroll")                                                      \
        for (int c = 0; c < 2; ++c) {                                          \
            const int p = c * 1024 + tid, r = p >> 3, kg = (p & 7) ^ (r & 7);  \
            gload16(arow + (size_t)r * DIM + (kt_) * BK + kg * 16,             \
                    &As[s_][p * 16]);                                          \
        }                                                                      \
    } while (0)

        STAGE_DG(0, 0);
        for (int kt = 0; kt < NKT; ++kt) {
            const int cur = kt & 1;
            if (kt + 1 < NKT) {
                STAGE_DG(kt + 1, cur ^ 1);
                asm volatile("s_waitcnt vmcnt(2)" ::: "memory");   // kt landed
            } else {
                asm volatile("s_waitcnt vmcnt(0)" ::: "memory");
            }
            BAR;
            const unsigned char* as = &As[cur][0];
            #pragma unroll
            for (int s = 0; s < 2; ++s) {
                i32x4 a[4], b[4];
                #pragma unroll
                for (int fi = 0; fi < 4; ++fi)
                    a[fi] = *reinterpret_cast<const i32x4*>(&as[rowA[fi] + xr[s]]);
                #pragma unroll
                for (int fj = 0; fj < 4; ++fj)
                    b[fj] = *reinterpret_cast<const i32x4*>(&as[rowB[fj] + xr[s]]);
                __builtin_amdgcn_s_setprio(1);
                #pragma unroll
                for (int fi = 0; fi < 4; ++fi)
                    #pragma unroll
                    for (int fj = 0; fj < 4; ++fj)
                        acc[fi][fj] = __builtin_amdgcn_mfma_i32_16x16x64_i8(
                            a[fi], b[fj], acc[fi][fj], 0, 0, 0);
                __builtin_amdgcn_s_setprio(0);
            }
            BAR;
        }
#undef STAGE_DG

        // Epilogue: col-side only (tile covers both (i,j) and (j,i)).
        int jc[4], tj[4];
        #pragma unroll
        for (int fj = 0; fj < 4; ++fj) {
            jc[fj] = colbase + wc * 64 + fj * 16 + l15;
            tj[fj] = tgt[jc[fj]];
        }
        float denc[4] = {0.f, 0.f, 0.f, 0.f};
        float posc[4] = {0.f, 0.f, 0.f, 0.f};
        #pragma unroll
        for (int fi = 0; fi < 4; ++fi) {
            const int ribase = rowbase + wr * 64 + fi * 16 + (l >> 4) * 4;
            const int4 tiv = *reinterpret_cast<const int4*>(&tgt[ribase]);
            const int tia[4] = {tiv.x, tiv.y, tiv.z, tiv.w};
            #pragma unroll
            for (int q = 0; q < 4; ++q) {
                const int gi = ribase + q;
                const int ti = tia[q];
                #pragma unroll
                for (int fj = 0; fj < 4; ++fj) {
                    const float sv = (float)acc[fi][fj][q] * INV_S;
                    const float pc = fmaxf(sv, 1e-10f);
                    const float e  = __expf(TEMP_INV * pc);
                    if (ti != tj[fj])        denc[fj] += e;
                    else if (gi != jc[fj])   posc[fj] += pc;
                }
            }
        }
        #pragma unroll
        for (int fj = 0; fj < 4; ++fj) {
            #pragma unroll
            for (int off = 16; off < 64; off <<= 1) {
                denc[fj] += __shfl_xor(denc[fj], off, 64);
                posc[fj] += __shfl_xor(posc[fj], off, 64);
            }
            if (l < 16) {
                atomicAdd(&denw[jc[fj]], denc[fj]);
                atomicAdd(&posw[jc[fj]], posc[fj]);
            }
        }
    }
}

// Single-block finalize: LDS class histogram + per-column loss + direct store.
__global__ __launch_bounds__(1024) void finalize_k(const float* __restrict__ posw,
                                                   const float* __restrict__ denw,
                                                   const int* __restrict__ tgt,
                                                   float* __restrict__ out) {
    __shared__ int hist[128];
    __shared__ float red[16];
    const int tid = threadIdx.x;
    if (tid < 128) hist[tid] = 0;
    __syncthreads();
    const int4 t4 = reinterpret_cast<const int4*>(tgt)[tid];
    atomicAdd(&hist[t4.x], 1);
    atomicAdd(&hist[t4.y], 1);
    atomicAdd(&hist[t4.z], 1);
    atomicAdd(&hist[t4.w], 1);
    __syncthreads();
    const int ta[4] = {t4.x, t4.y, t4.z, t4.w};
    float v = 0.0f;
    #pragma unroll
    for (int q = 0; q < 4; ++q) {
        const int j = tid * 4 + q;
        const float d = fmaxf(denw[j], 1e-10f);
        const float c = (float)(hist[ta[q]] - 1);
        v += TEMP_INV * posw[j] - c * __logf(d);
    }
    #pragma unroll
    for (int off = 32; off; off >>= 1) v += __shfl_xor(v, off, 64);
    if ((tid & 63) == 0) red[tid >> 6] = v;
    __syncthreads();
    if (tid == 0) {
        float s = 0.0f;
        #pragma unroll
        for (int i = 0; i < 16; ++i) s += red[i];
        out[0] = -s * (1.0f / 4096.0f);
    }
}

extern "C" void kernel_launch(void* const* d_in, const int* in_sizes, int n_in,
                              void* d_out, int out_size, void* d_ws, size_t ws_size,
                              hipStream_t stream) {
    const float* pred = (const float*)d_in[0];
    const int*   tgt  = (const int*)d_in[1];
    float* out = (float*)d_out;

    unsigned char* xn = (unsigned char*)d_ws;                        // 4 MB int8
    float* posw = (float*)((char*)d_ws + (size_t)NROWS * DIM);
    float* denw = posw + NROWS;

    normalize_k<<<NROWS, 256, 0, stream>>>(pred, xn, posw, denw);

    fused_gram<<<256, 1024, 0, stream>>>(xn, tgt, posw, denw);       // 256 blocks

    finalize_k<<<1, 1024, 0, stream>>>(posw, denw, tgt, out);
}

// Round 21
// 35.127 us; speedup vs baseline: 1.5417x; 1.2730x over previous
//
#include <hip/hip_runtime.h>
#include <hip/hip_bf16.h>

#define NROWS 4096
#define DIM   1024           // K elements; 1024 B/row in int8
#define BT    256            // full tile edge
#define BH    128            // half-tile column width
#define BK    128            // K-step (128 B = 128 k-elems)
#define NKT   (DIM / BK)     // 8 K-steps
#define NTB   (NROWS / BT)   // 16
#define NOFF  240            // 120 strict-upper tiles x 2 column-halves
#define TEMP_INV 10.0f
#define INV_S 3.814697e-6f   // 1/(512*512): int8 stored as round(512*x)

typedef int i32x4 __attribute__((ext_vector_type(4)));

__device__ __forceinline__ void gload16(const void* g, void* l) {
    __builtin_amdgcn_global_load_lds(
        (const __attribute__((address_space(1))) void*)g,
        (__attribute__((address_space(3))) void*)l, 16, 0, 0);
}

// Row-normalize fp32 -> int8 (round(512*x/||x||), clamp +-127), ONE ROW PER
// WAVE: pure 64-lane shuffle reduction, no LDS, no __syncthreads, 1/4 the
// blocks of the per-row-block version (overhead trim; math proven R15/R17).
__global__ __launch_bounds__(256) void normalize_k(const float* __restrict__ pred,
                                                   unsigned char* __restrict__ xn,
                                                   float* __restrict__ posw,
                                                   float* __restrict__ denw) {
    const int wv  = threadIdx.x >> 6;            // wave 0..3
    const int l   = threadIdx.x & 63;
    const int row = blockIdx.x * 4 + wv;
    const float4* src = reinterpret_cast<const float4*>(pred + (size_t)row * DIM);

    float4 v[4];
    float ss = 0.0f;
    #pragma unroll
    for (int c = 0; c < 4; ++c) {
        v[c] = src[l + 64 * c];                  // coalesced 16B/lane
        ss += v[c].x * v[c].x + v[c].y * v[c].y + v[c].z * v[c].z + v[c].w * v[c].w;
    }
    #pragma unroll
    for (int off = 32; off; off >>= 1) ss += __shfl_xor(ss, off, 64);
    const float scale = 512.0f / fmaxf(sqrtf(ss), 1e-8f);

    int* dst = reinterpret_cast<int*>(xn) + row * (DIM / 4);
    #pragma unroll
    for (int c = 0; c < 4; ++c) {
        int q0 = __float2int_rn(v[c].x * scale);
        int q1 = __float2int_rn(v[c].y * scale);
        int q2 = __float2int_rn(v[c].z * scale);
        int q3 = __float2int_rn(v[c].w * scale);
        q0 = min(max(q0, -127), 127); q1 = min(max(q1, -127), 127);
        q2 = min(max(q2, -127), 127); q3 = min(max(q3, -127), 127);
        dst[l + 64 * c] = (q0 & 0xFF) | ((q1 & 0xFF) << 8) |
                          ((q2 & 0xFF) << 16) | ((q3 & 0xFF) << 24);
    }
    if (l == 0) { posw[row] = 0.0f; denw[row] = 0.0f; }
}

#define BAR asm volatile("s_barrier" ::: "memory")

// Triangular int8 Gram + contrastive epilogue, 256 equally-loaded blocks.
// BYTE-IDENTICAL to R17 (best measured: gram ~23us, absmax 0.0):
//   ids 0..239  : strict-upper tile (bi<bj) column-half, output 256x128;
//                 stages A 32KB + B 16KB = 48KB/step; col-side AND mirror
//                 row-side partials (Gram symmetry).
//   ids 240..255: diagonal tile, full 256^2, stages A only (B == A).
// Counted-vmcnt pipeline, 0-conflict granule swizzle (kg^=r&7 pre-applied
// on the global source).  __launch_bounds__(512,2) REQUIRED: without it
// the 1024-thread default caps VGPR at 64 -> acc spills (R16, 150us);
// with it the int8 MFMA acc lives in AGPRs (R15/R17, no spill).
// Staging is pinned at the measured ~24 GB/s/CU ingest cap — invariant to
// pipeline depth (R18), wave count (R20), and dtype >= int8 (R9/R12).
__global__ __launch_bounds__(512, 2) void fused_gram(
        const unsigned char* __restrict__ xn, const int* __restrict__ tgt,
        float* __restrict__ posw, float* __restrict__ denw) {
    __shared__ unsigned char As[2][BT * BK];   // 2 x 32 KB
    __shared__ unsigned char Bs[2][BH * BK];   // 2 x 16 KB  (96 KB total)

    const int tid = threadIdx.x;
    const int w   = tid >> 6;
    const int l   = tid & 63;
    const int l15 = l & 15;
    const int kgl = l >> 4;
    const int swz = l15 & 7;

    int xr[2];
    #pragma unroll
    for (int s = 0; s < 2; ++s) xr[s] = ((s * 4 + kgl) ^ swz) * 16;

    if ((int)blockIdx.x < NOFF) {
        // ---------------- off-diagonal column-half ----------------
        const int t = ((int)blockIdx.x & 7) * (NOFF / 8) + ((int)blockIdx.x >> 3);
        const int tau = t >> 1, half = t & 1;
        int bi = 0, rem = tau;
        while (rem >= NTB - 1 - bi) { rem -= NTB - 1 - bi; ++bi; }
        const int bj = bi + 1 + rem;
        const int rowbase = bi * BT;
        const int colbase = bj * BT + half * BH;

        const int wm = w >> 1;       // 0..3 (64-row band)
        const int wn = w & 1;        // 0..1 (64-col band)

        const unsigned char* arow = xn + (size_t)rowbase * DIM;
        const unsigned char* bcol = xn + (size_t)colbase * DIM;

        int rowA[4], rowB[4];
        #pragma unroll
        for (int fi = 0; fi < 4; ++fi) rowA[fi] = (wm * 64 + fi * 16 + l15) * BK;
        #pragma unroll
        for (int fj = 0; fj < 4; ++fj) rowB[fj] = (wn * 64 + fj * 16 + l15) * BK;

        i32x4 acc[4][4];
        #pragma unroll
        for (int i = 0; i < 4; ++i)
            #pragma unroll
            for (int j = 0; j < 4; ++j) acc[i][j] = (i32x4){0, 0, 0, 0};

#define STAGE_OD(kt_, s_)                                                      \
    do {                                                                       \
        _Pragma("unroll")                                                      \
        for (int c = 0; c < 4; ++c) {                                          \
            const int p = c * 512 + tid, r = p >> 3, kg = (p & 7) ^ (r & 7);   \
            gload16(arow + (size_t)r * DIM + (kt_) * BK + kg * 16,             \
                    &As[s_][p * 16]);                                          \
        }                                                                      \
        _Pragma("unroll")                                                      \
        for (int c = 0; c < 2; ++c) {                                          \
            const int p = c * 512 + tid, r = p >> 3, kg = (p & 7) ^ (r & 7);   \
            gload16(bcol + (size_t)r * DIM + (kt_) * BK + kg * 16,             \
                    &Bs[s_][p * 16]);                                          \
        }                                                                      \
    } while (0)

        STAGE_OD(0, 0);
        for (int kt = 0; kt < NKT; ++kt) {
            const int cur = kt & 1;
            if (kt + 1 < NKT) {
                STAGE_OD(kt + 1, cur ^ 1);
                asm volatile("s_waitcnt vmcnt(6)" ::: "memory");
            } else {
                asm volatile("s_waitcnt vmcnt(0)" ::: "memory");
            }
            BAR;
            const unsigned char* as = &As[cur][0];
            const unsigned char* bs = &Bs[cur][0];
            #pragma unroll
            for (int s = 0; s < 2; ++s) {
                i32x4 a[4], b[4];
                #pragma unroll
                for (int fi = 0; fi < 4; ++fi)
                    a[fi] = *reinterpret_cast<const i32x4*>(&as[rowA[fi] + xr[s]]);
                #pragma unroll
                for (int fj = 0; fj < 4; ++fj)
                    b[fj] = *reinterpret_cast<const i32x4*>(&bs[rowB[fj] + xr[s]]);
                __builtin_amdgcn_s_setprio(1);
                #pragma unroll
                for (int fi = 0; fi < 4; ++fi)
                    #pragma unroll
                    for (int fj = 0; fj < 4; ++fj)
                        acc[fi][fj] = __builtin_amdgcn_mfma_i32_16x16x64_i8(
                            a[fi], b[fj], acc[fi][fj], 0, 0, 0);
                __builtin_amdgcn_s_setprio(0);
            }
            BAR;
        }
#undef STAGE_OD

        // Epilogue: col-side + mirror row-side (verified R2/R16/R17).
        int jc[4], tj[4];
        #pragma unroll
        for (int fj = 0; fj < 4; ++fj) {
            jc[fj] = colbase + wn * 64 + fj * 16 + l15;
            tj[fj] = tgt[jc[fj]];
        }
        float denc[4] = {0.f, 0.f, 0.f, 0.f};
        float posc[4] = {0.f, 0.f, 0.f, 0.f};
        #pragma unroll
        for (int fi = 0; fi < 4; ++fi) {
            const int ribase = rowbase + wm * 64 + fi * 16 + (l >> 4) * 4;
            const int4 tiv = *reinterpret_cast<const int4*>(&tgt[ribase]);
            const int tia[4] = {tiv.x, tiv.y, tiv.z, tiv.w};
            float denr[4] = {0.f, 0.f, 0.f, 0.f};
            float posr[4] = {0.f, 0.f, 0.f, 0.f};
            #pragma unroll
            for (int q = 0; q < 4; ++q) {
                const int ti = tia[q];
                #pragma unroll
                for (int fj = 0; fj < 4; ++fj) {
                    const float sv = (float)acc[fi][fj][q] * INV_S;
                    const float pc = fmaxf(sv, 1e-10f);
                    const float e  = __expf(TEMP_INV * pc);
                    if (ti != tj[fj]) { denc[fj] += e;  denr[q] += e; }
                    else              { posc[fj] += pc; posr[q] += pc; }
                }
            }
            #pragma unroll
            for (int q = 0; q < 4; ++q) {
                #pragma unroll
                for (int off = 1; off < 16; off <<= 1) {
                    denr[q] += __shfl_xor(denr[q], off, 64);
                    posr[q] += __shfl_xor(posr[q], off, 64);
                }
            }
            if (l15 == 0) {
                #pragma unroll
                for (int q = 0; q < 4; ++q) {
                    atomicAdd(&denw[ribase + q], denr[q]);
                    atomicAdd(&posw[ribase + q], posr[q]);
                }
            }
        }
        #pragma unroll
        for (int fj = 0; fj < 4; ++fj) {
            #pragma unroll
            for (int off = 16; off < 64; off <<= 1) {
                denc[fj] += __shfl_xor(denc[fj], off, 64);
                posc[fj] += __shfl_xor(posc[fj], off, 64);
            }
            if (l < 16) {
                atomicAdd(&denw[jc[fj]], denc[fj]);
                atomicAdd(&posw[jc[fj]], posc[fj]);
            }
        }
    } else {
        // ---------------- diagonal tile (full 256^2, B == A) ----------------
        const int d = (int)blockIdx.x - NOFF;
        const int rowbase = d * BT;
        const int colbase = rowbase;
        const int wr = w >> 2;       // 0..1 (128-row band)
        const int wc = w & 3;        // 0..3 (64-col band)

        const unsigned char* arow = xn + (size_t)rowbase * DIM;

        int rowA[8], rowB[4];
        #pragma unroll
        for (int fi = 0; fi < 8; ++fi) rowA[fi] = (wr * 128 + fi * 16 + l15) * BK;
        #pragma unroll
        for (int fj = 0; fj < 4; ++fj) rowB[fj] = (wc * 64 + fj * 16 + l15) * BK;

        i32x4 acc[8][4];
        #pragma unroll
        for (int i = 0; i < 8; ++i)
            #pragma unroll
            for (int j = 0; j < 4; ++j) acc[i][j] = (i32x4){0, 0, 0, 0};

#define STAGE_DG(kt_, s_)                                                      \
    do {                                                                       \
        _Pragma("unroll")                                                      \
        for (int c = 0; c < 4; ++c) {                                          \
            const int p = c * 512 + tid, r = p >> 3, kg = (p & 7) ^ (r & 7);   \
            gload16(arow + (size_t)r * DIM + (kt_) * BK + kg * 16,             \
                    &As[s_][p * 16]);                                          \
        }                                                                      \
    } while (0)

        STAGE_DG(0, 0);
        for (int kt = 0; kt < NKT; ++kt) {
            const int cur = kt & 1;
            if (kt + 1 < NKT) {
                STAGE_DG(kt + 1, cur ^ 1);
                asm volatile("s_waitcnt vmcnt(4)" ::: "memory");
            } else {
                asm volatile("s_waitcnt vmcnt(0)" ::: "memory");
            }
            BAR;
            const unsigned char* as = &As[cur][0];
            #pragma unroll
            for (int s = 0; s < 2; ++s) {
                i32x4 a[8], b[4];
                #pragma unroll
                for (int fi = 0; fi < 8; ++fi)
                    a[fi] = *reinterpret_cast<const i32x4*>(&as[rowA[fi] + xr[s]]);
                #pragma unroll
                for (int fj = 0; fj < 4; ++fj)
                    b[fj] = *reinterpret_cast<const i32x4*>(&as[rowB[fj] + xr[s]]);
                __builtin_amdgcn_s_setprio(1);
                #pragma unroll
                for (int fi = 0; fi < 8; ++fi)
                    #pragma unroll
                    for (int fj = 0; fj < 4; ++fj)
                        acc[fi][fj] = __builtin_amdgcn_mfma_i32_16x16x64_i8(
                            a[fi], b[fj], acc[fi][fj], 0, 0, 0);
                __builtin_amdgcn_s_setprio(0);
            }
            BAR;
        }
#undef STAGE_DG

        // Epilogue: col-side only (tile covers both (i,j) and (j,i)).
        int jc[4], tj[4];
        #pragma unroll
        for (int fj = 0; fj < 4; ++fj) {
            jc[fj] = colbase + wc * 64 + fj * 16 + l15;
            tj[fj] = tgt[jc[fj]];
        }
        float denc[4] = {0.f, 0.f, 0.f, 0.f};
        float posc[4] = {0.f, 0.f, 0.f, 0.f};
        #pragma unroll
        for (int fi = 0; fi < 8; ++fi) {
            const int ribase = rowbase + wr * 128 + fi * 16 + (l >> 4) * 4;
            const int4 tiv = *reinterpret_cast<const int4*>(&tgt[ribase]);
            const int tia[4] = {tiv.x, tiv.y, tiv.z, tiv.w};
            #pragma unroll
            for (int q = 0; q < 4; ++q) {
                const int gi = ribase + q;
                const int ti = tia[q];
                #pragma unroll
                for (int fj = 0; fj < 4; ++fj) {
                    const float sv = (float)acc[fi][fj][q] * INV_S;
                    const float pc = fmaxf(sv, 1e-10f);
                    const float e  = __expf(TEMP_INV * pc);
                    if (ti != tj[fj])        denc[fj] += e;
                    else if (gi != jc[fj])   posc[fj] += pc;
                }
            }
        }
        #pragma unroll
        for (int fj = 0; fj < 4; ++fj) {
            #pragma unroll
            for (int off = 16; off < 64; off <<= 1) {
                denc[fj] += __shfl_xor(denc[fj], off, 64);
                posc[fj] += __shfl_xor(posc[fj], off, 64);
            }
            if (l < 16) {
                atomicAdd(&denw[jc[fj]], denc[fj]);
                atomicAdd(&posw[jc[fj]], posc[fj]);
            }
        }
    }
}

// Single-block finalize: LDS class histogram + per-column loss + direct store.
__global__ __launch_bounds__(1024) void finalize_k(const float* __restrict__ posw,
                                                   const float* __restrict__ denw,
                                                   const int* __restrict__ tgt,
                                                   float* __restrict__ out) {
    __shared__ int hist[128];
    __shared__ float red[16];
    const int tid = threadIdx.x;
    if (tid < 128) hist[tid] = 0;
    __syncthreads();
    const int4 t4 = reinterpret_cast<const int4*>(tgt)[tid];
    atomicAdd(&hist[t4.x], 1);
    atomicAdd(&hist[t4.y], 1);
    atomicAdd(&hist[t4.z], 1);
    atomicAdd(&hist[t4.w], 1);
    __syncthreads();
    const int ta[4] = {t4.x, t4.y, t4.z, t4.w};
    float v = 0.0f;
    #pragma unroll
    for (int q = 0; q < 4; ++q) {
        const int j = tid * 4 + q;
        const float d = fmaxf(denw[j], 1e-10f);
        const float c = (float)(hist[ta[q]] - 1);
        v += TEMP_INV * posw[j] - c * __logf(d);
    }
    #pragma unroll
    for (int off = 32; off; off >>= 1) v += __shfl_xor(v, off, 64);
    if ((tid & 63) == 0) red[tid >> 6] = v;
    __syncthreads();
    if (tid == 0) {
        float s = 0.0f;
        #pragma unroll
        for (int i = 0; i < 16; ++i) s += red[i];
        out[0] = -s * (1.0f / 4096.0f);
    }
}

extern "C" void kernel_launch(void* const* d_in, const int* in_sizes, int n_in,
                              void* d_out, int out_size, void* d_ws, size_t ws_size,
                              hipStream_t stream) {
    const float* pred = (const float*)d_in[0];
    const int*   tgt  = (const int*)d_in[1];
    float* out = (float*)d_out;

    unsigned char* xn = (unsigned char*)d_ws;                        // 4 MB int8
    float* posw = (float*)((char*)d_ws + (size_t)NROWS * DIM);
    float* denw = posw + NROWS;

    normalize_k<<<NROWS / 4, 256, 0, stream>>>(pred, xn, posw, denw);

    fused_gram<<<256, 512, 0, stream>>>(xn, tgt, posw, denw);        // 256 blocks

    finalize_k<<<1, 1024, 0, stream>>>(posw, denw, tgt, out);
}